// Round 1
// baseline (350.065 us; speedup 1.0000x reference)
//
#include <hip/hip_runtime.h>

#define Bdim 256
#define Tdim 512
#define Kdim 128

// One block per batch element. Thread j owns state/column j.
// alpha kept in LINEAR space (A = exp(alpha - offset)), E = exp(trans) in
// per-thread registers (column j = 128 VGPRs). Per step:
//   A_new[j] = (sum_i A[i] * E[i][j]) * exp(logit[t][j] - log(A[0]))
//   offset  += log(A[0])
// A broadcast via double-buffered LDS, one barrier per step.
__global__ __launch_bounds__(128, 1) void crf_nll_kernel(
    const float* __restrict__ logits,   // B*T*K fp32
    const int*   __restrict__ labels,   // B*T   int32
    const int*   __restrict__ seq_lens, // B     int32
    const float* __restrict__ trans,    // K*K   fp32
    float* __restrict__ out)            // 1     fp32 (pre-zeroed)
{
    const int b = blockIdx.x;
    const int j = threadIdx.x;          // 0..127
    const int L = seq_lens[b];          // 1..T (uniform per block)

    __shared__ float pbuf[2][Kdim];
    __shared__ float red[2];

    const int*   lab_b   = labels + (size_t)b * Tdim;
    const float* logit_b = logits + (size_t)b * Tdim * Kdim;

    // ---- E column j into registers: e[i] = exp(trans[i][j]) ----
    float e[Kdim];
    #pragma unroll
    for (int i = 0; i < Kdim; ++i)
        e[i] = __expf(trans[i * Kdim + j]);

    // ---- gold-path score: unary + pairwise, masked by t < L ----
    float s = 0.f;
    #pragma unroll
    for (int t = j; t < Tdim; t += Kdim) {   // 4 iters per thread
        if (t < L) {
            int lb = lab_b[t];
            s += logit_b[(size_t)t * Kdim + lb];
            if (t >= 1)
                s += trans[lab_b[t - 1] * Kdim + lb];
        }
    }
    #pragma unroll
    for (int o = 32; o > 0; o >>= 1)
        s += __shfl_down(s, o, 64);
    if ((j & 63) == 0) red[j >> 6] = s;

    // ---- init alpha (t = 0), linear space ----
    float a = __expf(logit_b[j]);
    pbuf[0][j] = a;
    float off = 0.f;
    int cb = 0;
    __syncthreads();
    const float score = red[0] + red[1];     // uniform; used by thread 0

    // ---- prefetch first logit chunk (t = 1..8) ----
    float curl[8], nxtl[8];
    #pragma unroll
    for (int u = 0; u < 8; ++u) {
        int tt = 1 + u;
        curl[u] = (tt < Tdim) ? logit_b[(size_t)tt * Kdim + j] : 0.f;
    }

    // ---- forward recursion, stop at L (mask freezes alpha past L) ----
    for (int tb = 1; tb < L; tb += 8) {
        #pragma unroll
        for (int u = 0; u < 8; ++u) {        // prefetch next chunk
            int tt = tb + 8 + u;
            nxtl[u] = (tt < Tdim) ? logit_b[(size_t)tt * Kdim + j] : 0.f;
        }
        #pragma unroll
        for (int u = 0; u < 8; ++u) {
            const int t = tb + u;
            if (t < L) {                     // uniform per block
                const float4* p4 = (const float4*)pbuf[cb];
                float p0 = 1.f;
                float acc0 = 0.f, acc1 = 0.f;
                #pragma unroll
                for (int i4 = 0; i4 < Kdim / 4; ++i4) {
                    float4 p = p4[i4];       // uniform addr -> LDS broadcast
                    if (i4 == 0) p0 = p.x;
                    acc0 = fmaf(p.x, e[4 * i4 + 0], acc0);
                    acc1 = fmaf(p.y, e[4 * i4 + 1], acc1);
                    acc0 = fmaf(p.z, e[4 * i4 + 2], acc0);
                    acc1 = fmaf(p.w, e[4 * i4 + 3], acc1);
                }
                float acc = acc0 + acc1;
                float lp0 = __logf(p0);      // renormalizer (uniform)
                a = acc * __expf(curl[u] - lp0);
                off += lp0;
                pbuf[cb ^ 1][j] = a;
                cb ^= 1;
                __syncthreads();             // one barrier per step
            }
        }
        #pragma unroll
        for (int u = 0; u < 8; ++u) curl[u] = nxtl[u];
    }

    // ---- log_z = off + log(sum_j A[j]); nll = log_z - score ----
    float as = a;
    #pragma unroll
    for (int o = 32; o > 0; o >>= 1)
        as += __shfl_down(as, o, 64);
    __syncthreads();
    if ((j & 63) == 0) red[j >> 6] = as;
    __syncthreads();
    if (j == 0) {
        float logz = off + __logf(red[0] + red[1]);
        atomicAdd(out, logz - score);
    }
}

extern "C" void kernel_launch(void* const* d_in, const int* in_sizes, int n_in,
                              void* d_out, int out_size, void* d_ws, size_t ws_size,
                              hipStream_t stream) {
    const float* logits   = (const float*)d_in[0];
    const int*   labels   = (const int*)d_in[1];
    const int*   seq_lens = (const int*)d_in[2];
    const float* trans    = (const float*)d_in[3];
    float* out = (float*)d_out;

    hipMemsetAsync(out, 0, sizeof(float), stream);
    crf_nll_kernel<<<dim3(Bdim), dim3(Kdim), 0, stream>>>(
        logits, labels, seq_lens, trans, out);
}